// Round 10
// baseline (161.383 us; speedup 1.0000x reference)
//
#include <hip/hip_runtime.h>

#define N_NODES 65536
#define N_EDGES 1048576
#define D 64
#define NB 256                  // major buckets = dst >> 8
#define CHUNK (N_EDGES / NB)    // 4096 edges per passA workgroup
#define SSTAGE 6144             // LDS staging capacity in bucketB
#define FBCAP 65536             // fallback capacity per bucket (ws scratch)
#define PLANEU (N_NODES * 8)    // u32s per feature-quarter plane (2 MB)

typedef __bf16 bf16x8 __attribute__((ext_vector_type(8)));
typedef float f32x4 __attribute__((ext_vector_type(4)));

__device__ __forceinline__ int edge_at(const void* ei, int is64, long long pos) {
    if (is64) return (int)((const long long*)ei)[pos];
    return ((const int*)ei)[pos];
}

// Inline int64/int32 detection (hi word of int64 indices < 2^17 is always 0).
__device__ __forceinline__ int detect_is64(const unsigned* ei, int* s_is64) {
    if (threadIdx.x < 64) {
        unsigned v = ei[2 * threadIdx.x + 1];
        unsigned long long nz = __ballot(v != 0u);
        if (threadIdx.x == 0) *s_is64 = (nz == 0ull) ? 1 : 0;
    }
    __syncthreads();
    return *s_is64;
}

// ---------------------------------------------------------------------------
// Pass A: stage chunk in LDS packed (src | dst<<16), LDS hist over dst>>8,
// LDS scan, LDS bucket-sort, coalesced write-out. Also accumulates global
// per-bucket totals tot[256] (replaces the old scanT kernel).
// ---------------------------------------------------------------------------
__global__ __launch_bounds__(256) void passA_kernel(const void* ei,
                                                    unsigned* __restrict__ H,
                                                    unsigned* __restrict__ L,
                                                    unsigned* __restrict__ tot,
                                                    unsigned* __restrict__ pairs_cs) {
    __shared__ unsigned ed[CHUNK];
    __shared__ unsigned srt[CHUNK];
    __shared__ unsigned hist[NB];
    __shared__ unsigned scn[NB];
    __shared__ int s_is64;
    const int is64 = detect_is64((const unsigned*)ei, &s_is64);
    const int t = threadIdx.x;
    const int w = blockIdx.x;
    hist[t] = 0;
    __syncthreads();
    const int base = w * CHUNK;
    for (int i = t; i < CHUNK; i += 256) {
        unsigned src = (unsigned)edge_at(ei, is64, base + i);
        unsigned dst = (unsigned)edge_at(ei, is64, (long long)N_EDGES + base + i);
        ed[i] = src | (dst << 16);
        atomicAdd(&hist[dst >> 8], 1u);
    }
    __syncthreads();
    const unsigned own = hist[t];
    scn[t] = own;
    __syncthreads();
    for (int off = 1; off < NB; off <<= 1) {
        unsigned v = (t >= off) ? scn[t - off] : 0u;
        __syncthreads();
        scn[t] += v;
        __syncthreads();
    }
    const unsigned excl = scn[t] - own;
    H[t * NB + w] = own;
    L[t * NB + w] = excl;
    atomicAdd(&tot[t], own);
    hist[t] = excl;  // reuse as cursor
    __syncthreads();
    for (int i = t; i < CHUNK; i += 256) {
        unsigned p = ed[i];
        unsigned pos = atomicAdd(&hist[p >> 24], 1u);  // bucket = dst>>8 = p>>24
        srt[pos] = p;
    }
    __syncthreads();
    for (int i = t; i < CHUNK; i += 256) pairs_cs[(size_t)w * CHUNK + i] = srt[i];
}

// ---------------------------------------------------------------------------
// Pass B: scan tot -> bucket_start (locally), gather this bucket's 256
// chunk-runs into LDS, hist over dstlow (== deg), LDS scan -> row_start,
// LDS sort -> coalesced u16 src16, then prefolded y (4 feature planes).
// ---------------------------------------------------------------------------
__global__ __launch_bounds__(256) void bucketB_kernel(const unsigned* __restrict__ pairs_cs,
                                                      const unsigned* __restrict__ H,
                                                      const unsigned* __restrict__ L,
                                                      const unsigned* __restrict__ tot,
                                                      const float* __restrict__ x,
                                                      unsigned* __restrict__ row_start,
                                                      unsigned short* __restrict__ src16,
                                                      unsigned* __restrict__ y32,
                                                      unsigned* __restrict__ fb) {
    __shared__ unsigned s_pairs[SSTAGE];
    __shared__ unsigned short s_src[SSTAGE];
    __shared__ unsigned hist[NB];
    __shared__ unsigned scn[NB];
    __shared__ unsigned degs[NB];
    __shared__ unsigned s_tot[NB];
    const int t = threadIdx.x;
    const int b = blockIdx.x;

    // bucket_start via LDS scan of tot (identical in every block).
    s_tot[t] = tot[t];
    scn[t] = s_tot[t];
    __syncthreads();
    for (int off = 1; off < NB; off <<= 1) {
        unsigned v = (t >= off) ? scn[t - off] : 0u;
        __syncthreads();
        scn[t] += v;
        __syncthreads();
    }
    const unsigned base = scn[b] - s_tot[b];
    const unsigned cnt = s_tot[b];
    const bool staged = (cnt <= SSTAGE);
    __syncthreads();

    // run-gather: thread t copies chunk t's run for this bucket.
    const unsigned Hb = H[b * NB + t];
    const unsigned Lb = L[b * NB + t];
    scn[t] = Hb;
    __syncthreads();
    for (int off = 1; off < NB; off <<= 1) {
        unsigned v = (t >= off) ? scn[t - off] : 0u;
        __syncthreads();
        scn[t] += v;
        __syncthreads();
    }
    const unsigned ex = scn[t] - Hb;
    unsigned* wp = staged ? s_pairs : (fb + (size_t)b * FBCAP);
    for (unsigned j = 0; j < Hb; ++j) wp[ex + j] = pairs_cs[(size_t)t * CHUNK + Lb + j];
    __syncthreads();
    const unsigned* pp = staged ? s_pairs : (fb + (size_t)b * FBCAP);

    hist[t] = 0;
    __syncthreads();
    for (unsigned i = t; i < cnt; i += 256u) {
        atomicAdd(&hist[(pp[i] >> 16) & 255u], 1u);
    }
    __syncthreads();
    const unsigned own = hist[t];
    degs[t] = own;
    scn[t] = own;
    __syncthreads();
    for (int off = 1; off < NB; off <<= 1) {
        unsigned v = (t >= off) ? scn[t - off] : 0u;
        __syncthreads();
        scn[t] += v;
        __syncthreads();
    }
    const unsigned excl = scn[t] - own;
    row_start[b * NB + t] = base + excl;
    if (b == NB - 1 && t == 0) row_start[N_NODES] = N_EDGES;
    hist[t] = excl;  // reuse as cursor
    __syncthreads();
    if (staged) {
        for (unsigned i = t; i < cnt; i += 256u) {
            unsigned p = pp[i];
            unsigned pos = atomicAdd(&hist[(p >> 16) & 255u], 1u);
            s_src[pos] = (unsigned short)(p & 0xFFFFu);
        }
        __syncthreads();
        for (unsigned i = t; i < cnt; i += 256u) src16[base + i] = s_src[i];
    } else {  // statistically unreachable
        for (unsigned i = t; i < cnt; i += 256u) {
            unsigned p = pp[i];
            unsigned pos = atomicAdd(&hist[(p >> 16) & 255u], 1u);
            src16[base + pos] = (unsigned short)(p & 0xFFFFu);
        }
    }
    // y phase: y[n][d] = bf16(rsqrt(deg[n]) * x[n][d]), 4 feature planes.
    const int nbase = b * NB;
    for (int idx = t; idx < NB * 32; idx += 256) {
        int nl = idx >> 5;
        int col = idx & 31;               // u32 column 0..31 (2 feats each)
        unsigned d = degs[nl];
        float w = d ? rsqrtf((float)d) : 0.f;
        float2 v = *(const float2*)(x + (nbase + nl) * D + col * 2);
        unsigned lo = (unsigned)__builtin_bit_cast(unsigned short, (__bf16)(v.x * w));
        unsigned hi = (unsigned)__builtin_bit_cast(unsigned short, (__bf16)(v.y * w));
        y32[(size_t)(col >> 3) * PLANEU + (size_t)(nbase + nl) * 8 + (col & 7)] =
            lo | (hi << 16);
    }
}

// ---------------------------------------------------------------------------
// SpMM over prefolded bf16 y, feature-quarter split + XCD pinning.
// Quarter q = (blockIdx&7)>>1: with round-robin block->XCD dispatch each XCD
// pair gathers only its own 2 MB plane (fits per-XCD L2). Wave = 16 edge
// slots x 4 lanes x uint2 (32 B/edge-row). h written plane-split bf16.
// ---------------------------------------------------------------------------
#define BLO(u) __uint_as_float((u) << 16)
#define BHI(u) __uint_as_float((u) & 0xffff0000u)
__device__ __forceinline__ unsigned pkbf(float lo, float hi) {
    return (unsigned)__builtin_bit_cast(unsigned short, (__bf16)lo) |
           ((unsigned)__builtin_bit_cast(unsigned short, (__bf16)hi) << 16);
}
__global__ __launch_bounds__(256) void spmm_kernel(const unsigned short* __restrict__ src16,
                                                   const unsigned* __restrict__ row_start,
                                                   const unsigned* __restrict__ y32,
                                                   unsigned* __restrict__ hb) {
    const int lane = threadIdx.x & 63;
    const int wv = threadIdx.x >> 6;
    const int grp = lane >> 2;   // edge slot 0..15
    const int r4 = lane & 3;     // 8B slice of the 32B quarter row
    const int q = (blockIdx.x & 7) >> 1;
    const unsigned* yq = y32 + (size_t)q * PLANEU;
    unsigned* hq = hb + (size_t)q * PLANEU;
    const int rank = ((blockIdx.x >> 3) << 1) | (blockIdx.x & 1);  // 0..nrq-1
    const int nw = (int)(gridDim.x >> 1);  // waves per quarter (gridDim%8==0)
    int wid = rank * 4 + wv;
    for (int n = wid; n < N_NODES; n += nw) {
        const unsigned start = row_start[n];
        const unsigned end = row_start[n + 1];
        float a0 = 0.f, a1 = 0.f, a2 = 0.f, a3 = 0.f;
        for (unsigned i = start; i < end; i += 16u) {
            unsigned idx = i + grp;
            if (idx < end) {
                int s = (int)src16[idx];
                uint2 p = *(const uint2*)(yq + s * 8 + r4 * 2);
                a0 += BLO(p.x); a1 += BHI(p.x);
                a2 += BLO(p.y); a3 += BHI(p.y);
            }
        }
        a0 += __shfl_xor(a0, 4); a0 += __shfl_xor(a0, 8); a0 += __shfl_xor(a0, 16); a0 += __shfl_xor(a0, 32);
        a1 += __shfl_xor(a1, 4); a1 += __shfl_xor(a1, 8); a1 += __shfl_xor(a1, 16); a1 += __shfl_xor(a1, 32);
        a2 += __shfl_xor(a2, 4); a2 += __shfl_xor(a2, 8); a2 += __shfl_xor(a2, 16); a2 += __shfl_xor(a2, 32);
        a3 += __shfl_xor(a3, 4); a3 += __shfl_xor(a3, 8); a3 += __shfl_xor(a3, 16); a3 += __shfl_xor(a3, 32);
        const float w = (end > start) ? rsqrtf((float)(end - start)) : 0.f;
        if (grp == 0) {
            uint2 v;
            v.x = pkbf(a0 * w, a1 * w);
            v.y = pkbf(a2 * w, a3 * w);
            *(uint2*)(hq + (size_t)n * 8 + r4 * 2) = v;
        }
    }
}

// out = leaky(h@W1+b1) + leaky((x*h)@W2+b2) via mfma_f32_16x16x32_bf16.
// h read from the 4 bf16 planes (A-frag bits used directly).
__global__ __launch_bounds__(256) void dense_mfma_kernel(const float* __restrict__ x,
                                                         const unsigned* __restrict__ hb,
                                                         const float* __restrict__ W1,
                                                         const float* __restrict__ b1,
                                                         const float* __restrict__ W2,
                                                         const float* __restrict__ b2,
                                                         float* __restrict__ out) {
    const int lane = threadIdx.x & 63;
    const int lo = lane & 15;
    const int hi = lane >> 4;

    bf16x8 bw1[2][4], bw2[2][4];
#pragma unroll
    for (int kt = 0; kt < 2; ++kt)
#pragma unroll
        for (int nt = 0; nt < 4; ++nt) {
            bf16x8 v1, v2;
#pragma unroll
            for (int j = 0; j < 8; ++j) {
                int k = kt * 32 + hi * 8 + j;
                int n = nt * 16 + lo;
                v1[j] = (__bf16)W1[k * D + n];
                v2[j] = (__bf16)W2[k * D + n];
            }
            bw1[kt][nt] = v1;
            bw2[kt][nt] = v2;
        }
    float bb1[4], bb2[4];
#pragma unroll
    for (int nt = 0; nt < 4; ++nt) {
        bb1[nt] = b1[nt * 16 + lo];
        bb2[nt] = b2[nt * 16 + lo];
    }

    int wid = (blockIdx.x * blockDim.x + threadIdx.x) >> 6;
    int nw = (gridDim.x * blockDim.x) >> 6;
    for (int blk = wid; blk < N_NODES / 16; blk += nw) {
        const int rb = blk * 16;
        // per-row base within a plane (u32 units); plane chosen per (kt,hi)
        const unsigned* hrowu = hb + (size_t)(rb + lo) * 8 + (hi & 1) * 4;
        const float* xrow = x + (rb + lo) * D;
        bf16x8 ah[2], ag[2];
#pragma unroll
        for (int kt = 0; kt < 2; ++kt) {
            const int c = kt * 32 + hi * 8;
            const int q = kt * 2 + (hi >> 1);
            uint4 hp = *(const uint4*)(hrowu + (size_t)q * PLANEU);
            float4 xv0 = *(const float4*)(xrow + c);
            float4 xv1 = *(const float4*)(xrow + c + 4);
            ah[kt] = __builtin_bit_cast(bf16x8, hp);
            bf16x8 g;
            g[0] = (__bf16)(BLO(hp.x) * xv0.x);
            g[1] = (__bf16)(BHI(hp.x) * xv0.y);
            g[2] = (__bf16)(BLO(hp.y) * xv0.z);
            g[3] = (__bf16)(BHI(hp.y) * xv0.w);
            g[4] = (__bf16)(BLO(hp.z) * xv1.x);
            g[5] = (__bf16)(BHI(hp.z) * xv1.y);
            g[6] = (__bf16)(BLO(hp.w) * xv1.z);
            g[7] = (__bf16)(BHI(hp.w) * xv1.w);
            ag[kt] = g;
        }
        f32x4 acc1[4], acc2[4];
#pragma unroll
        for (int nt = 0; nt < 4; ++nt) {
            acc1[nt] = (f32x4){0.f, 0.f, 0.f, 0.f};
            acc2[nt] = (f32x4){0.f, 0.f, 0.f, 0.f};
        }
#pragma unroll
        for (int kt = 0; kt < 2; ++kt)
#pragma unroll
            for (int nt = 0; nt < 4; ++nt) {
                acc1[nt] = __builtin_amdgcn_mfma_f32_16x16x32_bf16(ah[kt], bw1[kt][nt], acc1[nt], 0, 0, 0);
                acc2[nt] = __builtin_amdgcn_mfma_f32_16x16x32_bf16(ag[kt], bw2[kt][nt], acc2[nt], 0, 0, 0);
            }
#pragma unroll
        for (int nt = 0; nt < 4; ++nt)
#pragma unroll
            for (int r = 0; r < 4; ++r) {
                float a1 = acc1[nt][r] + bb1[nt];
                float a2 = acc2[nt][r] + bb2[nt];
                a1 = (a1 >= 0.f) ? a1 : 0.2f * a1;
                a2 = (a2 >= 0.f) ? a2 : 0.2f * a2;
                out[(rb + hi * 4 + r) * D + nt * 16 + lo] = a1 + a2;
            }
    }
}

extern "C" void kernel_launch(void* const* d_in, const int* in_sizes, int n_in,
                              void* d_out, int out_size, void* d_ws, size_t ws_size,
                              hipStream_t stream) {
    const float* x  = (const float*)d_in[0];
    const void*  ei = d_in[1];
    const float* W1 = (const float*)d_in[2];
    const float* b1 = (const float*)d_in[3];
    const float* W2 = (const float*)d_in[4];
    const float* b2 = (const float*)d_in[5];
    float* out = (float*)d_out;

    char* p = (char*)d_ws;
    unsigned* tot          = (unsigned*)p;       p += 4096;            // 256 u32
    unsigned* row_start    = (unsigned*)p;       p += 266240;          // 65537 u32
    unsigned* H            = (unsigned*)p;       p += NB * NB * 4;     // 256 KB
    unsigned* L            = (unsigned*)p;       p += NB * NB * 4;     // 256 KB
    unsigned short* src16  = (unsigned short*)p; p += (size_t)N_EDGES * 2;      // 2 MB
    unsigned* y32          = (unsigned*)p;       p += (size_t)4 * PLANEU * 4;   // 8 MB
    unsigned* hb           = (unsigned*)p;       p += (size_t)4 * PLANEU * 4;   // 8 MB
    unsigned* fb           = (unsigned*)p;       // 64 MB fallback (rarely touched)

    // pairs_cs scratch lives in d_out: written by passA, consumed by bucketB,
    // then d_out is fully overwritten by dense_mfma. Deterministic modulo
    // intra-run LDS-atomic order (rounding-level only, as in prior rounds).
    unsigned* pairs_cs = (unsigned*)d_out;

    hipMemsetAsync(tot, 0, NB * sizeof(unsigned), stream);
    passA_kernel<<<NB, 256, 0, stream>>>(ei, H, L, tot, pairs_cs);
    bucketB_kernel<<<NB, 256, 0, stream>>>(pairs_cs, H, L, tot, x,
                                           row_start, src16, y32, fb);
    spmm_kernel<<<4096, 256, 0, stream>>>(src16, row_start, y32, hb);
    dense_mfma_kernel<<<1024, 256, 0, stream>>>(x, hb, W1, b1, W2, b2, out);
}

// Round 11
// 107.176 us; speedup vs baseline: 1.5058x; 1.5058x over previous
//
#include <hip/hip_runtime.h>

#define N_NODES 65536
#define N_EDGES 1048576
#define D 64
#define NB 256                  // major buckets = dst >> 8
#define CHUNK (N_EDGES / NB)    // 4096 edges per passA workgroup
#define SSTAGE 6144             // LDS staging capacity in bucketB
#define FBCAP 65536             // fallback capacity per bucket (ws scratch)
#define PLANE2U (N_NODES * 16)  // u32s per feature-half plane (4 MB)

typedef __bf16 bf16x8 __attribute__((ext_vector_type(8)));
typedef float f32x4 __attribute__((ext_vector_type(4)));

__device__ __forceinline__ int edge_at(const void* ei, int is64, long long pos) {
    if (is64) return (int)((const long long*)ei)[pos];
    return ((const int*)ei)[pos];
}

// Inline int64/int32 detection (hi word of int64 indices < 2^17 is always 0).
__device__ __forceinline__ int detect_is64(const unsigned* ei, int* s_is64) {
    if (threadIdx.x < 64) {
        unsigned v = ei[2 * threadIdx.x + 1];
        unsigned long long nz = __ballot(v != 0u);
        if (threadIdx.x == 0) *s_is64 = (nz == 0ull) ? 1 : 0;
    }
    __syncthreads();
    return *s_is64;
}

// ---------------------------------------------------------------------------
// Pass A: stage chunk in LDS packed (src | dst<<16), LDS hist over dst>>8,
// LDS scan, LDS bucket-sort, coalesced write-out. Accumulates global
// per-bucket totals tot[256].
// ---------------------------------------------------------------------------
__global__ __launch_bounds__(256) void passA_kernel(const void* ei,
                                                    unsigned* __restrict__ H,
                                                    unsigned* __restrict__ L,
                                                    unsigned* __restrict__ tot,
                                                    unsigned* __restrict__ pairs_cs) {
    __shared__ unsigned ed[CHUNK];
    __shared__ unsigned srt[CHUNK];
    __shared__ unsigned hist[NB];
    __shared__ unsigned scn[NB];
    __shared__ int s_is64;
    const int is64 = detect_is64((const unsigned*)ei, &s_is64);
    const int t = threadIdx.x;
    const int w = blockIdx.x;
    hist[t] = 0;
    __syncthreads();
    const int base = w * CHUNK;
    for (int i = t; i < CHUNK; i += 256) {
        unsigned src = (unsigned)edge_at(ei, is64, base + i);
        unsigned dst = (unsigned)edge_at(ei, is64, (long long)N_EDGES + base + i);
        ed[i] = src | (dst << 16);
        atomicAdd(&hist[dst >> 8], 1u);
    }
    __syncthreads();
    const unsigned own = hist[t];
    scn[t] = own;
    __syncthreads();
    for (int off = 1; off < NB; off <<= 1) {
        unsigned v = (t >= off) ? scn[t - off] : 0u;
        __syncthreads();
        scn[t] += v;
        __syncthreads();
    }
    const unsigned excl = scn[t] - own;
    H[t * NB + w] = own;
    L[t * NB + w] = excl;
    atomicAdd(&tot[t], own);
    hist[t] = excl;  // reuse as cursor
    __syncthreads();
    for (int i = t; i < CHUNK; i += 256) {
        unsigned p = ed[i];
        unsigned pos = atomicAdd(&hist[p >> 24], 1u);  // bucket = dst>>8 = p>>24
        srt[pos] = p;
    }
    __syncthreads();
    for (int i = t; i < CHUNK; i += 256) pairs_cs[(size_t)w * CHUNK + i] = srt[i];
}

// ---------------------------------------------------------------------------
// Pass B: scan tot -> bucket_start (locally), gather this bucket's 256
// chunk-runs into LDS, hist over dstlow (== deg), LDS scan -> row_start,
// LDS sort -> coalesced u16 src16, then prefolded y (2 feature-half planes).
// ---------------------------------------------------------------------------
__global__ __launch_bounds__(256) void bucketB_kernel(const unsigned* __restrict__ pairs_cs,
                                                      const unsigned* __restrict__ H,
                                                      const unsigned* __restrict__ L,
                                                      const unsigned* __restrict__ tot,
                                                      const float* __restrict__ x,
                                                      unsigned* __restrict__ row_start,
                                                      unsigned short* __restrict__ src16,
                                                      unsigned* __restrict__ y32,
                                                      unsigned* __restrict__ fb) {
    __shared__ unsigned s_pairs[SSTAGE];
    __shared__ unsigned short s_src[SSTAGE];
    __shared__ unsigned hist[NB];
    __shared__ unsigned scn[NB];
    __shared__ unsigned degs[NB];
    __shared__ unsigned s_tot[NB];
    const int t = threadIdx.x;
    const int b = blockIdx.x;

    // bucket_start via LDS scan of tot (identical in every block).
    s_tot[t] = tot[t];
    scn[t] = s_tot[t];
    __syncthreads();
    for (int off = 1; off < NB; off <<= 1) {
        unsigned v = (t >= off) ? scn[t - off] : 0u;
        __syncthreads();
        scn[t] += v;
        __syncthreads();
    }
    const unsigned base = scn[b] - s_tot[b];
    const unsigned cnt = s_tot[b];
    const bool staged = (cnt <= SSTAGE);
    __syncthreads();

    // run-gather: thread t copies chunk t's run for this bucket.
    const unsigned Hb = H[b * NB + t];
    const unsigned Lb = L[b * NB + t];
    scn[t] = Hb;
    __syncthreads();
    for (int off = 1; off < NB; off <<= 1) {
        unsigned v = (t >= off) ? scn[t - off] : 0u;
        __syncthreads();
        scn[t] += v;
        __syncthreads();
    }
    const unsigned ex = scn[t] - Hb;
    unsigned* wp = staged ? s_pairs : (fb + (size_t)b * FBCAP);
    for (unsigned j = 0; j < Hb; ++j) wp[ex + j] = pairs_cs[(size_t)t * CHUNK + Lb + j];
    __syncthreads();
    const unsigned* pp = staged ? s_pairs : (fb + (size_t)b * FBCAP);

    hist[t] = 0;
    __syncthreads();
    for (unsigned i = t; i < cnt; i += 256u) {
        atomicAdd(&hist[(pp[i] >> 16) & 255u], 1u);
    }
    __syncthreads();
    const unsigned own = hist[t];
    degs[t] = own;
    scn[t] = own;
    __syncthreads();
    for (int off = 1; off < NB; off <<= 1) {
        unsigned v = (t >= off) ? scn[t - off] : 0u;
        __syncthreads();
        scn[t] += v;
        __syncthreads();
    }
    const unsigned excl = scn[t] - own;
    row_start[b * NB + t] = base + excl;
    if (b == NB - 1 && t == 0) row_start[N_NODES] = N_EDGES;
    hist[t] = excl;  // reuse as cursor
    __syncthreads();
    if (staged) {
        for (unsigned i = t; i < cnt; i += 256u) {
            unsigned p = pp[i];
            unsigned pos = atomicAdd(&hist[(p >> 16) & 255u], 1u);
            s_src[pos] = (unsigned short)(p & 0xFFFFu);
        }
        __syncthreads();
        for (unsigned i = t; i < cnt; i += 256u) src16[base + i] = s_src[i];
    } else {  // statistically unreachable
        for (unsigned i = t; i < cnt; i += 256u) {
            unsigned p = pp[i];
            unsigned pos = atomicAdd(&hist[(p >> 16) & 255u], 1u);
            src16[base + pos] = (unsigned short)(p & 0xFFFFu);
        }
    }
    // y phase: y[n][d] = bf16(rsqrt(deg[n]) * x[n][d]), 2 half planes.
    const int nbase = b * NB;
    for (int idx = t; idx < NB * 32; idx += 256) {
        int nl = idx >> 5;
        int col = idx & 31;               // u32 column 0..31 (2 feats each)
        unsigned d = degs[nl];
        float w = d ? rsqrtf((float)d) : 0.f;
        float2 v = *(const float2*)(x + (nbase + nl) * D + col * 2);
        unsigned lo = (unsigned)__builtin_bit_cast(unsigned short, (__bf16)(v.x * w));
        unsigned hi = (unsigned)__builtin_bit_cast(unsigned short, (__bf16)(v.y * w));
        y32[(size_t)(col >> 4) * PLANE2U + (size_t)(nbase + nl) * 16 + (col & 15)] =
            lo | (hi << 16);
    }
}

// ---------------------------------------------------------------------------
// SpMM over prefolded bf16 y, feature-HALF split + XCD pinning.
// half = (bid&7)>>2: XCDs 0-3 gather plane 0, XCDs 4-7 plane 1; each 4 MB
// plane fits one XCD L2. Wave = 16 edge slots x 4 lanes x uint4 (16 B/lane,
// 64-B half-row), unroll-2 = 32 edges with 2 outstanding loads. Every node
// processed exactly once per half (rank bijective, nw = 8192).
// ---------------------------------------------------------------------------
#define BLO(u) __uint_as_float((u) << 16)
#define BHI(u) __uint_as_float((u) & 0xffff0000u)
__device__ __forceinline__ unsigned pkbf(float lo, float hi) {
    return (unsigned)__builtin_bit_cast(unsigned short, (__bf16)lo) |
           ((unsigned)__builtin_bit_cast(unsigned short, (__bf16)hi) << 16);
}
__global__ __launch_bounds__(256) void spmm_kernel(const unsigned short* __restrict__ src16,
                                                   const unsigned* __restrict__ row_start,
                                                   const unsigned* __restrict__ y32,
                                                   uint4* __restrict__ hb4) {
    const int lane = threadIdx.x & 63;
    const int wv = threadIdx.x >> 6;
    const int grp = lane >> 2;   // edge slot 0..15
    const int r4 = lane & 3;     // uint4 slice of the 64-B half-row
    const int half = (blockIdx.x & 7) >> 2;
    const unsigned* yq = y32 + (size_t)half * PLANE2U;
    const int rank = ((blockIdx.x >> 3) << 2) | (blockIdx.x & 3);  // 0..2047
    const int nw = 8192;         // waves per half (gridDim == 4096)
    int wid = rank * 4 + wv;
    for (int n = wid; n < N_NODES; n += nw) {
        const unsigned start = row_start[n];
        const unsigned end = row_start[n + 1];
        float a0 = 0.f, a1 = 0.f, a2 = 0.f, a3 = 0.f;
        float a4 = 0.f, a5 = 0.f, a6 = 0.f, a7 = 0.f;
        float c0 = 0.f, c1 = 0.f, c2 = 0.f, c3 = 0.f;
        float c4 = 0.f, c5 = 0.f, c6 = 0.f, c7 = 0.f;
        unsigned i = start;
        for (; i + 32 <= end; i += 32) {
            int sA = (int)src16[i + grp];
            int sB = (int)src16[i + 16 + grp];
            uint4 pA = *(const uint4*)(yq + (size_t)sA * 16 + r4 * 4);
            uint4 pB = *(const uint4*)(yq + (size_t)sB * 16 + r4 * 4);
            a0 += BLO(pA.x); a1 += BHI(pA.x);
            a2 += BLO(pA.y); a3 += BHI(pA.y);
            a4 += BLO(pA.z); a5 += BHI(pA.z);
            a6 += BLO(pA.w); a7 += BHI(pA.w);
            c0 += BLO(pB.x); c1 += BHI(pB.x);
            c2 += BLO(pB.y); c3 += BHI(pB.y);
            c4 += BLO(pB.z); c5 += BHI(pB.z);
            c6 += BLO(pB.w); c7 += BHI(pB.w);
        }
        for (; i < end; i += 16) {
            if (i + grp < end) {
                int s = (int)src16[i + grp];
                uint4 p = *(const uint4*)(yq + (size_t)s * 16 + r4 * 4);
                a0 += BLO(p.x); a1 += BHI(p.x);
                a2 += BLO(p.y); a3 += BHI(p.y);
                a4 += BLO(p.z); a5 += BHI(p.z);
                a6 += BLO(p.w); a7 += BHI(p.w);
            }
        }
        a0 += c0; a1 += c1; a2 += c2; a3 += c3;
        a4 += c4; a5 += c5; a6 += c6; a7 += c7;
        a0 += __shfl_xor(a0, 4); a0 += __shfl_xor(a0, 8); a0 += __shfl_xor(a0, 16); a0 += __shfl_xor(a0, 32);
        a1 += __shfl_xor(a1, 4); a1 += __shfl_xor(a1, 8); a1 += __shfl_xor(a1, 16); a1 += __shfl_xor(a1, 32);
        a2 += __shfl_xor(a2, 4); a2 += __shfl_xor(a2, 8); a2 += __shfl_xor(a2, 16); a2 += __shfl_xor(a2, 32);
        a3 += __shfl_xor(a3, 4); a3 += __shfl_xor(a3, 8); a3 += __shfl_xor(a3, 16); a3 += __shfl_xor(a3, 32);
        a4 += __shfl_xor(a4, 4); a4 += __shfl_xor(a4, 8); a4 += __shfl_xor(a4, 16); a4 += __shfl_xor(a4, 32);
        a5 += __shfl_xor(a5, 4); a5 += __shfl_xor(a5, 8); a5 += __shfl_xor(a5, 16); a5 += __shfl_xor(a5, 32);
        a6 += __shfl_xor(a6, 4); a6 += __shfl_xor(a6, 8); a6 += __shfl_xor(a6, 16); a6 += __shfl_xor(a6, 32);
        a7 += __shfl_xor(a7, 4); a7 += __shfl_xor(a7, 8); a7 += __shfl_xor(a7, 16); a7 += __shfl_xor(a7, 32);
        const float w = (end > start) ? rsqrtf((float)(end - start)) : 0.f;
        if (grp == 0) {  // lanes 0..3 hold the reduced half-row
            uint4 v;
            v.x = pkbf(a0 * w, a1 * w);
            v.y = pkbf(a2 * w, a3 * w);
            v.z = pkbf(a4 * w, a5 * w);
            v.w = pkbf(a6 * w, a7 * w);
            hb4[(size_t)n * 8 + half * 4 + r4] = v;  // unified h layout
        }
    }
}

// out = leaky(h@W1+b1) + leaky((x*h)@W2+b2) via mfma_f32_16x16x32_bf16.
// h read as packed bf16, unified layout (round-8 proven version).
__global__ __launch_bounds__(256) void dense_mfma_kernel(const float* __restrict__ x,
                                                         const uint4* __restrict__ hb4,
                                                         const float* __restrict__ W1,
                                                         const float* __restrict__ b1,
                                                         const float* __restrict__ W2,
                                                         const float* __restrict__ b2,
                                                         float* __restrict__ out) {
    const int lane = threadIdx.x & 63;
    const int lo = lane & 15;
    const int hi = lane >> 4;

    bf16x8 bw1[2][4], bw2[2][4];
#pragma unroll
    for (int kt = 0; kt < 2; ++kt)
#pragma unroll
        for (int nt = 0; nt < 4; ++nt) {
            bf16x8 v1, v2;
#pragma unroll
            for (int j = 0; j < 8; ++j) {
                int k = kt * 32 + hi * 8 + j;
                int n = nt * 16 + lo;
                v1[j] = (__bf16)W1[k * D + n];
                v2[j] = (__bf16)W2[k * D + n];
            }
            bw1[kt][nt] = v1;
            bw2[kt][nt] = v2;
        }
    float bb1[4], bb2[4];
#pragma unroll
    for (int nt = 0; nt < 4; ++nt) {
        bb1[nt] = b1[nt * 16 + lo];
        bb2[nt] = b2[nt * 16 + lo];
    }

    int wid = (blockIdx.x * blockDim.x + threadIdx.x) >> 6;
    int nw = (gridDim.x * blockDim.x) >> 6;
    for (int blk = wid; blk < N_NODES / 16; blk += nw) {
        const int rb = blk * 16;
        const uint4* hrow = hb4 + (size_t)(rb + lo) * 8;
        const float* xrow = x + (rb + lo) * D;
        bf16x8 ah[2], ag[2];
#pragma unroll
        for (int kt = 0; kt < 2; ++kt) {
            const int c = kt * 32 + hi * 8;
            uint4 hp = hrow[kt * 4 + hi];
            float4 xv0 = *(const float4*)(xrow + c);
            float4 xv1 = *(const float4*)(xrow + c + 4);
            ah[kt] = __builtin_bit_cast(bf16x8, hp);
            bf16x8 g;
            g[0] = (__bf16)(BLO(hp.x) * xv0.x);
            g[1] = (__bf16)(BHI(hp.x) * xv0.y);
            g[2] = (__bf16)(BLO(hp.y) * xv0.z);
            g[3] = (__bf16)(BHI(hp.y) * xv0.w);
            g[4] = (__bf16)(BLO(hp.z) * xv1.x);
            g[5] = (__bf16)(BHI(hp.z) * xv1.y);
            g[6] = (__bf16)(BLO(hp.w) * xv1.z);
            g[7] = (__bf16)(BHI(hp.w) * xv1.w);
            ag[kt] = g;
        }
        f32x4 acc1[4], acc2[4];
#pragma unroll
        for (int nt = 0; nt < 4; ++nt) {
            acc1[nt] = (f32x4){0.f, 0.f, 0.f, 0.f};
            acc2[nt] = (f32x4){0.f, 0.f, 0.f, 0.f};
        }
#pragma unroll
        for (int kt = 0; kt < 2; ++kt)
#pragma unroll
            for (int nt = 0; nt < 4; ++nt) {
                acc1[nt] = __builtin_amdgcn_mfma_f32_16x16x32_bf16(ah[kt], bw1[kt][nt], acc1[nt], 0, 0, 0);
                acc2[nt] = __builtin_amdgcn_mfma_f32_16x16x32_bf16(ag[kt], bw2[kt][nt], acc2[nt], 0, 0, 0);
            }
#pragma unroll
        for (int nt = 0; nt < 4; ++nt)
#pragma unroll
            for (int r = 0; r < 4; ++r) {
                float a1 = acc1[nt][r] + bb1[nt];
                float a2 = acc2[nt][r] + bb2[nt];
                a1 = (a1 >= 0.f) ? a1 : 0.2f * a1;
                a2 = (a2 >= 0.f) ? a2 : 0.2f * a2;
                out[(rb + hi * 4 + r) * D + nt * 16 + lo] = a1 + a2;
            }
    }
}

extern "C" void kernel_launch(void* const* d_in, const int* in_sizes, int n_in,
                              void* d_out, int out_size, void* d_ws, size_t ws_size,
                              hipStream_t stream) {
    const float* x  = (const float*)d_in[0];
    const void*  ei = d_in[1];
    const float* W1 = (const float*)d_in[2];
    const float* b1 = (const float*)d_in[3];
    const float* W2 = (const float*)d_in[4];
    const float* b2 = (const float*)d_in[5];
    float* out = (float*)d_out;

    char* p = (char*)d_ws;
    unsigned* tot          = (unsigned*)p;       p += 4096;            // 256 u32
    unsigned* row_start    = (unsigned*)p;       p += 266240;          // 65537 u32
    unsigned* H            = (unsigned*)p;       p += NB * NB * 4;     // 256 KB
    unsigned* L            = (unsigned*)p;       p += NB * NB * 4;     // 256 KB
    unsigned short* src16  = (unsigned short*)p; p += (size_t)N_EDGES * 2;      // 2 MB
    unsigned* y32          = (unsigned*)p;       p += (size_t)2 * PLANE2U * 4;  // 8 MB
    unsigned* hb           = (unsigned*)p;       p += (size_t)N_NODES * 32 * 4; // 8 MB
    unsigned* fb           = (unsigned*)p;       // 64 MB fallback (rarely touched)

    // pairs_cs scratch lives in d_out: written by passA, consumed by bucketB,
    // then d_out is fully overwritten by dense_mfma. Deterministic modulo
    // intra-run LDS-atomic order (rounding-level only, as in prior rounds).
    unsigned* pairs_cs = (unsigned*)d_out;

    hipMemsetAsync(tot, 0, NB * sizeof(unsigned), stream);
    passA_kernel<<<NB, 256, 0, stream>>>(ei, H, L, tot, pairs_cs);
    bucketB_kernel<<<NB, 256, 0, stream>>>(pairs_cs, H, L, tot, x,
                                           row_start, src16, y32, fb);
    spmm_kernel<<<4096, 256, 0, stream>>>(src16, row_start, y32, (uint4*)hb);
    dense_mfma_kernel<<<1024, 256, 0, stream>>>(x, (const uint4*)hb, W1, b1, W2, b2, out);
}

// Round 12
// 82.197 us; speedup vs baseline: 1.9634x; 1.3039x over previous
//
#include <hip/hip_runtime.h>

#define N_NODES 65536
#define N_EDGES 1048576
#define D 64
#define NB 256                  // major buckets = dst >> 8
#define CHUNK (N_EDGES / NB)    // 4096 edges per passA workgroup
#define SSTAGE 6144             // LDS staging capacity in bucketB
#define FBCAP 65536             // fallback capacity per bucket (ws scratch)

typedef __bf16 bf16x8 __attribute__((ext_vector_type(8)));
typedef float f32x4 __attribute__((ext_vector_type(4)));

__device__ __forceinline__ int edge_at(const void* ei, int is64, long long pos) {
    if (is64) return (int)((const long long*)ei)[pos];
    return ((const int*)ei)[pos];
}

// Inline int64/int32 detection (hi word of int64 indices < 2^17 is always 0).
__device__ __forceinline__ int detect_is64(const unsigned* ei, int* s_is64) {
    if (threadIdx.x < 64) {
        unsigned v = ei[2 * threadIdx.x + 1];
        unsigned long long nz = __ballot(v != 0u);
        if (threadIdx.x == 0) *s_is64 = (nz == 0ull) ? 1 : 0;
    }
    __syncthreads();
    return *s_is64;
}

// ---------------------------------------------------------------------------
// Pass A: stage chunk in LDS packed (src | dst<<16), LDS hist over dst>>8,
// LDS scan, LDS bucket-sort, coalesced write-out.
// Emits: pairs_cs[w*CHUNK + i], H[b*NB+w] (run length), L[b*NB+w] (run start).
// ---------------------------------------------------------------------------
__global__ __launch_bounds__(256) void passA_kernel(const void* ei,
                                                    unsigned* __restrict__ H,
                                                    unsigned* __restrict__ L,
                                                    unsigned* __restrict__ pairs_cs) {
    __shared__ unsigned ed[CHUNK];
    __shared__ unsigned srt[CHUNK];
    __shared__ unsigned hist[NB];
    __shared__ unsigned scn[NB];
    __shared__ int s_is64;
    const int is64 = detect_is64((const unsigned*)ei, &s_is64);
    const int t = threadIdx.x;
    const int w = blockIdx.x;
    hist[t] = 0;
    __syncthreads();
    const int base = w * CHUNK;
    for (int i = t; i < CHUNK; i += 256) {
        unsigned src = (unsigned)edge_at(ei, is64, base + i);
        unsigned dst = (unsigned)edge_at(ei, is64, (long long)N_EDGES + base + i);
        ed[i] = src | (dst << 16);
        atomicAdd(&hist[dst >> 8], 1u);
    }
    __syncthreads();
    const unsigned own = hist[t];
    scn[t] = own;
    __syncthreads();
    for (int off = 1; off < NB; off <<= 1) {
        unsigned v = (t >= off) ? scn[t - off] : 0u;
        __syncthreads();
        scn[t] += v;
        __syncthreads();
    }
    const unsigned excl = scn[t] - own;
    H[t * NB + w] = own;
    L[t * NB + w] = excl;
    hist[t] = excl;  // reuse as cursor
    __syncthreads();
    for (int i = t; i < CHUNK; i += 256) {
        unsigned p = ed[i];
        unsigned pos = atomicAdd(&hist[p >> 24], 1u);  // bucket = dst>>8 = p>>24
        srt[pos] = p;
    }
    __syncthreads();
    for (int i = t; i < CHUNK; i += 256) pairs_cs[(size_t)w * CHUNK + i] = srt[i];
}

// ---------------------------------------------------------------------------
// Pass B: bucket totals via per-thread H row-sum (H is L2-resident; replaces
// the old scanT kernel + memset), LDS scan -> bucket_start; gather this
// bucket's 256 chunk-runs into LDS, hist over dstlow (== deg), LDS scan ->
// row_start, LDS sort -> coalesced u16 src16, then prefolded bf16 y.
// ---------------------------------------------------------------------------
__global__ __launch_bounds__(256) void bucketB_kernel(const unsigned* __restrict__ pairs_cs,
                                                      const unsigned* __restrict__ H,
                                                      const unsigned* __restrict__ L,
                                                      const float* __restrict__ x,
                                                      unsigned* __restrict__ row_start,
                                                      unsigned short* __restrict__ src16,
                                                      unsigned* __restrict__ y32,
                                                      unsigned* __restrict__ fb) {
    __shared__ unsigned s_pairs[SSTAGE];
    __shared__ unsigned short s_src[SSTAGE];
    __shared__ unsigned hist[NB];
    __shared__ unsigned scn[NB];
    __shared__ unsigned degs[NB];
    __shared__ unsigned s_tot[NB];
    const int t = threadIdx.x;
    const int b = blockIdx.x;

    // bucket totals: thread t sums H[t][*] (1 KB contiguous, L2-hit).
    {
        const uint4* Hr = (const uint4*)(H + t * NB);
        unsigned tt = 0;
#pragma unroll 8
        for (int k = 0; k < NB / 4; ++k) {
            uint4 q = Hr[k];
            tt += q.x + q.y + q.z + q.w;
        }
        s_tot[t] = tt;
        scn[t] = tt;
    }
    __syncthreads();
    for (int off = 1; off < NB; off <<= 1) {
        unsigned v = (t >= off) ? scn[t - off] : 0u;
        __syncthreads();
        scn[t] += v;
        __syncthreads();
    }
    const unsigned base = scn[b] - s_tot[b];
    const unsigned cnt = s_tot[b];
    const bool staged = (cnt <= SSTAGE);
    __syncthreads();

    // run-gather: thread t copies chunk t's run for this bucket.
    const unsigned Hb = H[b * NB + t];
    const unsigned Lb = L[b * NB + t];
    scn[t] = Hb;
    __syncthreads();
    for (int off = 1; off < NB; off <<= 1) {
        unsigned v = (t >= off) ? scn[t - off] : 0u;
        __syncthreads();
        scn[t] += v;
        __syncthreads();
    }
    const unsigned ex = scn[t] - Hb;
    unsigned* wp = staged ? s_pairs : (fb + (size_t)b * FBCAP);
    for (unsigned j = 0; j < Hb; ++j) wp[ex + j] = pairs_cs[(size_t)t * CHUNK + Lb + j];
    __syncthreads();
    const unsigned* pp = staged ? s_pairs : (fb + (size_t)b * FBCAP);

    hist[t] = 0;
    __syncthreads();
    for (unsigned i = t; i < cnt; i += 256u) {
        atomicAdd(&hist[(pp[i] >> 16) & 255u], 1u);
    }
    __syncthreads();
    const unsigned own = hist[t];
    degs[t] = own;
    scn[t] = own;
    __syncthreads();
    for (int off = 1; off < NB; off <<= 1) {
        unsigned v = (t >= off) ? scn[t - off] : 0u;
        __syncthreads();
        scn[t] += v;
        __syncthreads();
    }
    const unsigned excl = scn[t] - own;
    row_start[b * NB + t] = base + excl;
    if (b == NB - 1 && t == 0) row_start[N_NODES] = N_EDGES;
    hist[t] = excl;  // reuse as cursor
    __syncthreads();
    if (staged) {
        for (unsigned i = t; i < cnt; i += 256u) {
            unsigned p = pp[i];
            unsigned pos = atomicAdd(&hist[(p >> 16) & 255u], 1u);
            s_src[pos] = (unsigned short)(p & 0xFFFFu);
        }
        __syncthreads();
        for (unsigned i = t; i < cnt; i += 256u) src16[base + i] = s_src[i];
    } else {  // statistically unreachable
        for (unsigned i = t; i < cnt; i += 256u) {
            unsigned p = pp[i];
            unsigned pos = atomicAdd(&hist[(p >> 16) & 255u], 1u);
            src16[base + pos] = (unsigned short)(p & 0xFFFFu);
        }
    }
    // y phase: y[n][d] = bf16(rsqrt(deg[n]) * x[n][d]), unified layout.
    const int nbase = b * NB;
    for (int idx = t; idx < NB * 32; idx += 256) {
        int nl = idx >> 5;
        int col = idx & 31;               // u32 column (2 feats each)
        unsigned d = degs[nl];
        float w = d ? rsqrtf((float)d) : 0.f;
        float2 v = *(const float2*)(x + (nbase + nl) * D + col * 2);
        unsigned lo = (unsigned)__builtin_bit_cast(unsigned short, (__bf16)(v.x * w));
        unsigned hi = (unsigned)__builtin_bit_cast(unsigned short, (__bf16)(v.y * w));
        y32[(size_t)(nbase + nl) * 32 + col] = lo | (hi << 16);
    }
}

// ---------------------------------------------------------------------------
// Atomic-free segmented SpMM over prefolded bf16 y; h stored packed bf16.
// Wave = 8 groups x 8 lanes; each group handles one edge slot, lane loads
// uint4 (8 bf16 feats). Single masked loop: BOTH uint4 loads issued every
// iteration with clamped index (clamped lanes hit the same line ~ free),
// adds predicated — 2 loads in flight for every node incl. deg<16.
// ---------------------------------------------------------------------------
#define BLO(u) __uint_as_float((u) << 16)
#define BHI(u) __uint_as_float((u) & 0xffff0000u)
__device__ __forceinline__ unsigned pkbf(float lo, float hi) {
    return (unsigned)__builtin_bit_cast(unsigned short, (__bf16)lo) |
           ((unsigned)__builtin_bit_cast(unsigned short, (__bf16)hi) << 16);
}
__global__ __launch_bounds__(256) void spmm_kernel(const unsigned short* __restrict__ src16,
                                                   const unsigned* __restrict__ row_start,
                                                   const uint4* __restrict__ y128,
                                                   uint4* __restrict__ hb4) {
    const int lane = threadIdx.x & 63;
    const int grp = lane >> 3;   // edge slot 0..7
    const int r8 = lane & 7;     // feature chunk [8*r8, 8*r8+8)
    int wid = (blockIdx.x * blockDim.x + threadIdx.x) >> 6;
    int nw = (gridDim.x * blockDim.x) >> 6;
    for (int n = wid; n < N_NODES; n += nw) {
        const unsigned start = row_start[n];
        const unsigned end = row_start[n + 1];
        float a0 = 0.f, a1 = 0.f, a2 = 0.f, a3 = 0.f;
        float a4 = 0.f, a5 = 0.f, a6 = 0.f, a7 = 0.f;
        float c0 = 0.f, c1 = 0.f, c2 = 0.f, c3 = 0.f;
        float c4 = 0.f, c5 = 0.f, c6 = 0.f, c7 = 0.f;
        for (unsigned i = start; i < end; i += 16u) {
            const unsigned e1 = end - 1u;
            const unsigned iA = i + grp;
            const unsigned iB = i + 8u + grp;
            int sA = (int)src16[iA < end ? iA : e1];
            int sB = (int)src16[iB < end ? iB : e1];
            uint4 pA = y128[sA * 8 + r8];
            uint4 pB = y128[sB * 8 + r8];
            if (iA < end) {
                a0 += BLO(pA.x); a1 += BHI(pA.x);
                a2 += BLO(pA.y); a3 += BHI(pA.y);
                a4 += BLO(pA.z); a5 += BHI(pA.z);
                a6 += BLO(pA.w); a7 += BHI(pA.w);
            }
            if (iB < end) {
                c0 += BLO(pB.x); c1 += BHI(pB.x);
                c2 += BLO(pB.y); c3 += BHI(pB.y);
                c4 += BLO(pB.z); c5 += BHI(pB.z);
                c6 += BLO(pB.w); c7 += BHI(pB.w);
            }
        }
        a0 += c0; a1 += c1; a2 += c2; a3 += c3;
        a4 += c4; a5 += c5; a6 += c6; a7 += c7;
        a0 += __shfl_xor(a0, 8); a0 += __shfl_xor(a0, 16); a0 += __shfl_xor(a0, 32);
        a1 += __shfl_xor(a1, 8); a1 += __shfl_xor(a1, 16); a1 += __shfl_xor(a1, 32);
        a2 += __shfl_xor(a2, 8); a2 += __shfl_xor(a2, 16); a2 += __shfl_xor(a2, 32);
        a3 += __shfl_xor(a3, 8); a3 += __shfl_xor(a3, 16); a3 += __shfl_xor(a3, 32);
        a4 += __shfl_xor(a4, 8); a4 += __shfl_xor(a4, 16); a4 += __shfl_xor(a4, 32);
        a5 += __shfl_xor(a5, 8); a5 += __shfl_xor(a5, 16); a5 += __shfl_xor(a5, 32);
        a6 += __shfl_xor(a6, 8); a6 += __shfl_xor(a6, 16); a6 += __shfl_xor(a6, 32);
        a7 += __shfl_xor(a7, 8); a7 += __shfl_xor(a7, 16); a7 += __shfl_xor(a7, 32);
        const float w = (end > start) ? rsqrtf((float)(end - start)) : 0.f;
        if (grp == 0) {
            uint4 v;
            v.x = pkbf(a0 * w, a1 * w);
            v.y = pkbf(a2 * w, a3 * w);
            v.z = pkbf(a4 * w, a5 * w);
            v.w = pkbf(a6 * w, a7 * w);
            hb4[(size_t)n * 8 + r8] = v;
        }
    }
}

// out = leaky(h@W1+b1) + leaky((x*h)@W2+b2) via mfma_f32_16x16x32_bf16.
// h read as packed bf16 (A-frag bits used directly).
__global__ __launch_bounds__(256) void dense_mfma_kernel(const float* __restrict__ x,
                                                         const uint4* __restrict__ hb4,
                                                         const float* __restrict__ W1,
                                                         const float* __restrict__ b1,
                                                         const float* __restrict__ W2,
                                                         const float* __restrict__ b2,
                                                         float* __restrict__ out) {
    const int lane = threadIdx.x & 63;
    const int lo = lane & 15;
    const int hi = lane >> 4;

    bf16x8 bw1[2][4], bw2[2][4];
#pragma unroll
    for (int kt = 0; kt < 2; ++kt)
#pragma unroll
        for (int nt = 0; nt < 4; ++nt) {
            bf16x8 v1, v2;
#pragma unroll
            for (int j = 0; j < 8; ++j) {
                int k = kt * 32 + hi * 8 + j;
                int n = nt * 16 + lo;
                v1[j] = (__bf16)W1[k * D + n];
                v2[j] = (__bf16)W2[k * D + n];
            }
            bw1[kt][nt] = v1;
            bw2[kt][nt] = v2;
        }
    float bb1[4], bb2[4];
#pragma unroll
    for (int nt = 0; nt < 4; ++nt) {
        bb1[nt] = b1[nt * 16 + lo];
        bb2[nt] = b2[nt * 16 + lo];
    }

    int wid = (blockIdx.x * blockDim.x + threadIdx.x) >> 6;
    int nw = (gridDim.x * blockDim.x) >> 6;
    for (int blk = wid; blk < N_NODES / 16; blk += nw) {
        const int rb = blk * 16;
        const uint4* hrow = hb4 + (size_t)(rb + lo) * 8;
        const float* xrow = x + (rb + lo) * D;
        bf16x8 ah[2], ag[2];
#pragma unroll
        for (int kt = 0; kt < 2; ++kt) {
            const int c = kt * 32 + hi * 8;
            uint4 hp = hrow[kt * 4 + hi];
            float4 xv0 = *(const float4*)(xrow + c);
            float4 xv1 = *(const float4*)(xrow + c + 4);
            ah[kt] = __builtin_bit_cast(bf16x8, hp);
            bf16x8 g;
            g[0] = (__bf16)(BLO(hp.x) * xv0.x);
            g[1] = (__bf16)(BHI(hp.x) * xv0.y);
            g[2] = (__bf16)(BLO(hp.y) * xv0.z);
            g[3] = (__bf16)(BHI(hp.y) * xv0.w);
            g[4] = (__bf16)(BLO(hp.z) * xv1.x);
            g[5] = (__bf16)(BHI(hp.z) * xv1.y);
            g[6] = (__bf16)(BLO(hp.w) * xv1.z);
            g[7] = (__bf16)(BHI(hp.w) * xv1.w);
            ag[kt] = g;
        }
        f32x4 acc1[4], acc2[4];
#pragma unroll
        for (int nt = 0; nt < 4; ++nt) {
            acc1[nt] = (f32x4){0.f, 0.f, 0.f, 0.f};
            acc2[nt] = (f32x4){0.f, 0.f, 0.f, 0.f};
        }
#pragma unroll
        for (int kt = 0; kt < 2; ++kt)
#pragma unroll
            for (int nt = 0; nt < 4; ++nt) {
                acc1[nt] = __builtin_amdgcn_mfma_f32_16x16x32_bf16(ah[kt], bw1[kt][nt], acc1[nt], 0, 0, 0);
                acc2[nt] = __builtin_amdgcn_mfma_f32_16x16x32_bf16(ag[kt], bw2[kt][nt], acc2[nt], 0, 0, 0);
            }
#pragma unroll
        for (int nt = 0; nt < 4; ++nt)
#pragma unroll
            for (int r = 0; r < 4; ++r) {
                float a1 = acc1[nt][r] + bb1[nt];
                float a2 = acc2[nt][r] + bb2[nt];
                a1 = (a1 >= 0.f) ? a1 : 0.2f * a1;
                a2 = (a2 >= 0.f) ? a2 : 0.2f * a2;
                out[(rb + hi * 4 + r) * D + nt * 16 + lo] = a1 + a2;
            }
    }
}

extern "C" void kernel_launch(void* const* d_in, const int* in_sizes, int n_in,
                              void* d_out, int out_size, void* d_ws, size_t ws_size,
                              hipStream_t stream) {
    const float* x  = (const float*)d_in[0];
    const void*  ei = d_in[1];
    const float* W1 = (const float*)d_in[2];
    const float* b1 = (const float*)d_in[3];
    const float* W2 = (const float*)d_in[4];
    const float* b2 = (const float*)d_in[5];
    float* out = (float*)d_out;

    char* p = (char*)d_ws;
    unsigned* row_start    = (unsigned*)p;       p += 266240;          // 65537 u32
    unsigned* H            = (unsigned*)p;       p += NB * NB * 4;     // 256 KB
    unsigned* L            = (unsigned*)p;       p += NB * NB * 4;     // 256 KB
    unsigned short* src16  = (unsigned short*)p; p += (size_t)N_EDGES * 2;      // 2 MB
    unsigned* y32          = (unsigned*)p;       p += (size_t)N_NODES * 32 * 4; // 8 MB
    unsigned* hb           = (unsigned*)p;       p += (size_t)N_NODES * 32 * 4; // 8 MB
    unsigned* fb           = (unsigned*)p;       // 64 MB fallback (rarely touched)

    // pairs_cs scratch lives in d_out: written by passA, consumed by bucketB,
    // then d_out is fully overwritten by dense_mfma. Deterministic modulo
    // intra-run LDS-atomic order (rounding-level only, as in prior rounds).
    unsigned* pairs_cs = (unsigned*)d_out;

    passA_kernel<<<NB, 256, 0, stream>>>(ei, H, L, pairs_cs);
    bucketB_kernel<<<NB, 256, 0, stream>>>(pairs_cs, H, L, x, row_start, src16, y32, fb);
    spmm_kernel<<<4096, 256, 0, stream>>>(src16, row_start, (const uint4*)y32, (uint4*)hb);
    dense_mfma_kernel<<<1024, 256, 0, stream>>>(x, (const uint4*)hb, W1, b1, W2, b2, out);
}

// Round 13
// 72.714 us; speedup vs baseline: 2.2194x; 1.1304x over previous
//
#include <hip/hip_runtime.h>

#define N_NODES 65536
#define N_EDGES 1048576
#define D 64
#define NB 256                  // major buckets = dst >> 8
#define CHUNK (N_EDGES / NB)    // 4096 edges per passA workgroup
#define SSTAGE 6144             // LDS staging capacity in bucketB
#define FBCAP 65536             // fallback capacity per bucket (ws scratch)

typedef __bf16 bf16x8 __attribute__((ext_vector_type(8)));
typedef float f32x4 __attribute__((ext_vector_type(4)));

__device__ __forceinline__ int edge_at(const void* ei, int is64, long long pos) {
    if (is64) return (int)((const long long*)ei)[pos];
    return ((const int*)ei)[pos];
}

// Inline int64/int32 detection (hi word of int64 indices < 2^17 is always 0).
__device__ __forceinline__ int detect_is64(const unsigned* ei, int* s_is64) {
    if (threadIdx.x < 64) {
        unsigned v = ei[2 * threadIdx.x + 1];
        unsigned long long nz = __ballot(v != 0u);
        if (threadIdx.x == 0) *s_is64 = (nz == 0ull) ? 1 : 0;
    }
    __syncthreads();
    return *s_is64;
}

// ---------------------------------------------------------------------------
// Pass A: stage chunk in LDS packed (src | dst<<16), LDS hist over dst>>8,
// LDS scan, LDS bucket-sort, coalesced write-out.
// Emits: pairs_cs[w*CHUNK + i], H[b*NB+w] (run length), L[b*NB+w] (run start).
// ---------------------------------------------------------------------------
__global__ __launch_bounds__(256) void passA_kernel(const void* ei,
                                                    unsigned* __restrict__ H,
                                                    unsigned* __restrict__ L,
                                                    unsigned* __restrict__ pairs_cs) {
    __shared__ unsigned ed[CHUNK];
    __shared__ unsigned srt[CHUNK];
    __shared__ unsigned hist[NB];
    __shared__ unsigned scn[NB];
    __shared__ int s_is64;
    const int is64 = detect_is64((const unsigned*)ei, &s_is64);
    const int t = threadIdx.x;
    const int w = blockIdx.x;
    hist[t] = 0;
    __syncthreads();
    const int base = w * CHUNK;
    for (int i = t; i < CHUNK; i += 256) {
        unsigned src = (unsigned)edge_at(ei, is64, base + i);
        unsigned dst = (unsigned)edge_at(ei, is64, (long long)N_EDGES + base + i);
        ed[i] = src | (dst << 16);
        atomicAdd(&hist[dst >> 8], 1u);
    }
    __syncthreads();
    const unsigned own = hist[t];
    scn[t] = own;
    __syncthreads();
    for (int off = 1; off < NB; off <<= 1) {
        unsigned v = (t >= off) ? scn[t - off] : 0u;
        __syncthreads();
        scn[t] += v;
        __syncthreads();
    }
    const unsigned excl = scn[t] - own;
    H[t * NB + w] = own;
    L[t * NB + w] = excl;
    hist[t] = excl;  // reuse as cursor
    __syncthreads();
    for (int i = t; i < CHUNK; i += 256) {
        unsigned p = ed[i];
        unsigned pos = atomicAdd(&hist[p >> 24], 1u);  // bucket = dst>>8 = p>>24
        srt[pos] = p;
    }
    __syncthreads();
    for (int i = t; i < CHUNK; i += 256) pairs_cs[(size_t)w * CHUNK + i] = srt[i];
}

// ---------------------------------------------------------------------------
// Pass B: bucket totals via per-thread H row-sum, LDS scan -> bucket_start;
// gather this bucket's 256 chunk-runs into LDS, hist over dstlow (== deg),
// LDS scan -> row_start, LDS sort -> coalesced u16 src16, prefolded bf16 y.
// ---------------------------------------------------------------------------
__global__ __launch_bounds__(256) void bucketB_kernel(const unsigned* __restrict__ pairs_cs,
                                                      const unsigned* __restrict__ H,
                                                      const unsigned* __restrict__ L,
                                                      const float* __restrict__ x,
                                                      unsigned* __restrict__ row_start,
                                                      unsigned short* __restrict__ src16,
                                                      unsigned* __restrict__ y32,
                                                      unsigned* __restrict__ fb) {
    __shared__ unsigned s_pairs[SSTAGE];
    __shared__ unsigned short s_src[SSTAGE];
    __shared__ unsigned hist[NB];
    __shared__ unsigned scn[NB];
    __shared__ unsigned degs[NB];
    __shared__ unsigned s_tot[NB];
    const int t = threadIdx.x;
    const int b = blockIdx.x;

    // bucket totals: thread t sums H[t][*] (1 KB contiguous, L2-hit).
    {
        const uint4* Hr = (const uint4*)(H + t * NB);
        unsigned tt = 0;
#pragma unroll 8
        for (int k = 0; k < NB / 4; ++k) {
            uint4 q = Hr[k];
            tt += q.x + q.y + q.z + q.w;
        }
        s_tot[t] = tt;
        scn[t] = tt;
    }
    __syncthreads();
    for (int off = 1; off < NB; off <<= 1) {
        unsigned v = (t >= off) ? scn[t - off] : 0u;
        __syncthreads();
        scn[t] += v;
        __syncthreads();
    }
    const unsigned base = scn[b] - s_tot[b];
    const unsigned cnt = s_tot[b];
    const bool staged = (cnt <= SSTAGE);
    __syncthreads();

    // run-gather: thread t copies chunk t's run for this bucket.
    const unsigned Hb = H[b * NB + t];
    const unsigned Lb = L[b * NB + t];
    scn[t] = Hb;
    __syncthreads();
    for (int off = 1; off < NB; off <<= 1) {
        unsigned v = (t >= off) ? scn[t - off] : 0u;
        __syncthreads();
        scn[t] += v;
        __syncthreads();
    }
    const unsigned ex = scn[t] - Hb;
    unsigned* wp = staged ? s_pairs : (fb + (size_t)b * FBCAP);
    for (unsigned j = 0; j < Hb; ++j) wp[ex + j] = pairs_cs[(size_t)t * CHUNK + Lb + j];
    __syncthreads();
    const unsigned* pp = staged ? s_pairs : (fb + (size_t)b * FBCAP);

    hist[t] = 0;
    __syncthreads();
    for (unsigned i = t; i < cnt; i += 256u) {
        atomicAdd(&hist[(pp[i] >> 16) & 255u], 1u);
    }
    __syncthreads();
    const unsigned own = hist[t];
    degs[t] = own;
    scn[t] = own;
    __syncthreads();
    for (int off = 1; off < NB; off <<= 1) {
        unsigned v = (t >= off) ? scn[t - off] : 0u;
        __syncthreads();
        scn[t] += v;
        __syncthreads();
    }
    const unsigned excl = scn[t] - own;
    row_start[b * NB + t] = base + excl;
    if (b == NB - 1 && t == 0) row_start[N_NODES] = N_EDGES;
    hist[t] = excl;  // reuse as cursor
    __syncthreads();
    if (staged) {
        for (unsigned i = t; i < cnt; i += 256u) {
            unsigned p = pp[i];
            unsigned pos = atomicAdd(&hist[(p >> 16) & 255u], 1u);
            s_src[pos] = (unsigned short)(p & 0xFFFFu);
        }
        __syncthreads();
        for (unsigned i = t; i < cnt; i += 256u) src16[base + i] = s_src[i];
    } else {  // statistically unreachable
        for (unsigned i = t; i < cnt; i += 256u) {
            unsigned p = pp[i];
            unsigned pos = atomicAdd(&hist[(p >> 16) & 255u], 1u);
            src16[base + pos] = (unsigned short)(p & 0xFFFFu);
        }
    }
    // y phase: y[n][d] = bf16(rsqrt(deg[n]) * x[n][d]), unified layout.
    const int nbase = b * NB;
    for (int idx = t; idx < NB * 32; idx += 256) {
        int nl = idx >> 5;
        int col = idx & 31;               // u32 column (2 feats each)
        unsigned d = degs[nl];
        float w = d ? rsqrtf((float)d) : 0.f;
        float2 v = *(const float2*)(x + (nbase + nl) * D + col * 2);
        unsigned lo = (unsigned)__builtin_bit_cast(unsigned short, (__bf16)(v.x * w));
        unsigned hi = (unsigned)__builtin_bit_cast(unsigned short, (__bf16)(v.y * w));
        y32[(size_t)(nbase + nl) * 32 + col] = lo | (hi << 16);
    }
}

// ---------------------------------------------------------------------------
// Atomic-free segmented SpMM, NO cross-lane reduction.
// Wave = 8 nodes x 8 lanes: 8-lane group g owns node nb+g entirely; lane r8
// owns feature chunk [8*r8, 8*r8+8) and serially walks the group's edge list
// (unroll-4: 4 uint4 loads in flight). Divergence across groups is
// exec-masked (idle lanes issue no loads -> exact gather bytes). Store:
// hb4[nb*8 + lane] = one coalesced 1 KB line per wave. Grid 2048 blocks =
// 8192 waves = exactly full chip residency, 8 nodes per wave.
// ---------------------------------------------------------------------------
#define BLO(u) __uint_as_float((u) << 16)
#define BHI(u) __uint_as_float((u) & 0xffff0000u)
__device__ __forceinline__ unsigned pkbf(float lo, float hi) {
    return (unsigned)__builtin_bit_cast(unsigned short, (__bf16)lo) |
           ((unsigned)__builtin_bit_cast(unsigned short, (__bf16)hi) << 16);
}
__device__ __forceinline__ void acc8(uint4 p, float* a) {
    a[0] += BLO(p.x); a[1] += BHI(p.x);
    a[2] += BLO(p.y); a[3] += BHI(p.y);
    a[4] += BLO(p.z); a[5] += BHI(p.z);
    a[6] += BLO(p.w); a[7] += BHI(p.w);
}
__global__ __launch_bounds__(256) void spmm_kernel(const unsigned short* __restrict__ src16,
                                                   const unsigned* __restrict__ row_start,
                                                   const uint4* __restrict__ y128,
                                                   uint4* __restrict__ hb4) {
    const int lane = threadIdx.x & 63;
    const int g = lane >> 3;     // node slot 0..7
    const int r8 = lane & 7;     // feature chunk [8*r8, 8*r8+8)
    int wv = (blockIdx.x * blockDim.x + threadIdx.x) >> 6;
    int nwv = (gridDim.x * blockDim.x) >> 6;
    for (int nb = wv * 8; nb < N_NODES; nb += nwv * 8) {
        const int n = nb + g;
        const unsigned start = row_start[n];
        const unsigned end = row_start[n + 1];
        float a[8] = {0.f, 0.f, 0.f, 0.f, 0.f, 0.f, 0.f, 0.f};
        float c[8] = {0.f, 0.f, 0.f, 0.f, 0.f, 0.f, 0.f, 0.f};
        unsigned i = start;
        for (; i + 4 <= end; i += 4) {
            int s0 = (int)src16[i];
            int s1 = (int)src16[i + 1];
            int s2 = (int)src16[i + 2];
            int s3 = (int)src16[i + 3];
            uint4 p0 = y128[s0 * 8 + r8];
            uint4 p1 = y128[s1 * 8 + r8];
            uint4 p2 = y128[s2 * 8 + r8];
            uint4 p3 = y128[s3 * 8 + r8];
            acc8(p0, a); acc8(p1, c);
            acc8(p2, a); acc8(p3, c);
        }
        for (; i < end; ++i) {
            uint4 p = y128[(int)src16[i] * 8 + r8];
            acc8(p, a);
        }
        const float w = (end > start) ? rsqrtf((float)(end - start)) : 0.f;
        uint4 v;
        v.x = pkbf((a[0] + c[0]) * w, (a[1] + c[1]) * w);
        v.y = pkbf((a[2] + c[2]) * w, (a[3] + c[3]) * w);
        v.z = pkbf((a[4] + c[4]) * w, (a[5] + c[5]) * w);
        v.w = pkbf((a[6] + c[6]) * w, (a[7] + c[7]) * w);
        hb4[(size_t)nb * 8 + lane] = v;  // n*8 + r8 == nb*8 + lane
    }
}

// out = leaky(h@W1+b1) + leaky((x*h)@W2+b2) via mfma_f32_16x16x32_bf16.
// h read as packed bf16 (A-frag bits used directly).
__global__ __launch_bounds__(256) void dense_mfma_kernel(const float* __restrict__ x,
                                                         const uint4* __restrict__ hb4,
                                                         const float* __restrict__ W1,
                                                         const float* __restrict__ b1,
                                                         const float* __restrict__ W2,
                                                         const float* __restrict__ b2,
                                                         float* __restrict__ out) {
    const int lane = threadIdx.x & 63;
    const int lo = lane & 15;
    const int hi = lane >> 4;

    bf16x8 bw1[2][4], bw2[2][4];
#pragma unroll
    for (int kt = 0; kt < 2; ++kt)
#pragma unroll
        for (int nt = 0; nt < 4; ++nt) {
            bf16x8 v1, v2;
#pragma unroll
            for (int j = 0; j < 8; ++j) {
                int k = kt * 32 + hi * 8 + j;
                int n = nt * 16 + lo;
                v1[j] = (__bf16)W1[k * D + n];
                v2[j] = (__bf16)W2[k * D + n];
            }
            bw1[kt][nt] = v1;
            bw2[kt][nt] = v2;
        }
    float bb1[4], bb2[4];
#pragma unroll
    for (int nt = 0; nt < 4; ++nt) {
        bb1[nt] = b1[nt * 16 + lo];
        bb2[nt] = b2[nt * 16 + lo];
    }

    int wid = (blockIdx.x * blockDim.x + threadIdx.x) >> 6;
    int nw = (gridDim.x * blockDim.x) >> 6;
    for (int blk = wid; blk < N_NODES / 16; blk += nw) {
        const int rb = blk * 16;
        const uint4* hrow = hb4 + (size_t)(rb + lo) * 8;
        const float* xrow = x + (rb + lo) * D;
        bf16x8 ah[2], ag[2];
#pragma unroll
        for (int kt = 0; kt < 2; ++kt) {
            const int c = kt * 32 + hi * 8;
            uint4 hp = hrow[kt * 4 + hi];
            float4 xv0 = *(const float4*)(xrow + c);
            float4 xv1 = *(const float4*)(xrow + c + 4);
            ah[kt] = __builtin_bit_cast(bf16x8, hp);
            bf16x8 g;
            g[0] = (__bf16)(BLO(hp.x) * xv0.x);
            g[1] = (__bf16)(BHI(hp.x) * xv0.y);
            g[2] = (__bf16)(BLO(hp.y) * xv0.z);
            g[3] = (__bf16)(BHI(hp.y) * xv0.w);
            g[4] = (__bf16)(BLO(hp.z) * xv1.x);
            g[5] = (__bf16)(BHI(hp.z) * xv1.y);
            g[6] = (__bf16)(BLO(hp.w) * xv1.z);
            g[7] = (__bf16)(BHI(hp.w) * xv1.w);
            ag[kt] = g;
        }
        f32x4 acc1[4], acc2[4];
#pragma unroll
        for (int nt = 0; nt < 4; ++nt) {
            acc1[nt] = (f32x4){0.f, 0.f, 0.f, 0.f};
            acc2[nt] = (f32x4){0.f, 0.f, 0.f, 0.f};
        }
#pragma unroll
        for (int kt = 0; kt < 2; ++kt)
#pragma unroll
            for (int nt = 0; nt < 4; ++nt) {
                acc1[nt] = __builtin_amdgcn_mfma_f32_16x16x32_bf16(ah[kt], bw1[kt][nt], acc1[nt], 0, 0, 0);
                acc2[nt] = __builtin_amdgcn_mfma_f32_16x16x32_bf16(ag[kt], bw2[kt][nt], acc2[nt], 0, 0, 0);
            }
#pragma unroll
        for (int nt = 0; nt < 4; ++nt)
#pragma unroll
            for (int r = 0; r < 4; ++r) {
                float a1 = acc1[nt][r] + bb1[nt];
                float a2 = acc2[nt][r] + bb2[nt];
                a1 = (a1 >= 0.f) ? a1 : 0.2f * a1;
                a2 = (a2 >= 0.f) ? a2 : 0.2f * a2;
                out[(rb + hi * 4 + r) * D + nt * 16 + lo] = a1 + a2;
            }
    }
}

extern "C" void kernel_launch(void* const* d_in, const int* in_sizes, int n_in,
                              void* d_out, int out_size, void* d_ws, size_t ws_size,
                              hipStream_t stream) {
    const float* x  = (const float*)d_in[0];
    const void*  ei = d_in[1];
    const float* W1 = (const float*)d_in[2];
    const float* b1 = (const float*)d_in[3];
    const float* W2 = (const float*)d_in[4];
    const float* b2 = (const float*)d_in[5];
    float* out = (float*)d_out;

    char* p = (char*)d_ws;
    unsigned* row_start    = (unsigned*)p;       p += 266240;          // 65537 u32
    unsigned* H            = (unsigned*)p;       p += NB * NB * 4;     // 256 KB
    unsigned* L            = (unsigned*)p;       p += NB * NB * 4;     // 256 KB
    unsigned short* src16  = (unsigned short*)p; p += (size_t)N_EDGES * 2;      // 2 MB
    unsigned* y32          = (unsigned*)p;       p += (size_t)N_NODES * 32 * 4; // 8 MB
    unsigned* hb           = (unsigned*)p;       p += (size_t)N_NODES * 32 * 4; // 8 MB
    unsigned* fb           = (unsigned*)p;       // 64 MB fallback (rarely touched)

    // pairs_cs scratch lives in d_out: written by passA, consumed by bucketB,
    // then d_out is fully overwritten by dense_mfma. Deterministic modulo
    // intra-run LDS-atomic order (rounding-level only, as in prior rounds).
    unsigned* pairs_cs = (unsigned*)d_out;

    passA_kernel<<<NB, 256, 0, stream>>>(ei, H, L, pairs_cs);
    bucketB_kernel<<<NB, 256, 0, stream>>>(pairs_cs, H, L, x, row_start, src16, y32, fb);
    spmm_kernel<<<2048, 256, 0, stream>>>(src16, row_start, (const uint4*)y32, (uint4*)hb);
    dense_mfma_kernel<<<1024, 256, 0, stream>>>(x, (const uint4*)hb, W1, b1, W2, b2, out);
}

// Round 14
// 71.841 us; speedup vs baseline: 2.2464x; 1.0122x over previous
//
#include <hip/hip_runtime.h>

#define N_NODES 65536
#define N_EDGES 1048576
#define D 64
#define NB 256                  // major buckets = dst >> 8
#define CHUNK (N_EDGES / NB)    // 4096 edges per passA workgroup
#define SSTAGE 6144             // LDS staging capacity in bucketB
#define FBCAP 65536             // fallback capacity per bucket (ws scratch)

typedef __bf16 bf16x8 __attribute__((ext_vector_type(8)));
typedef float f32x4 __attribute__((ext_vector_type(4)));

__device__ __forceinline__ int edge_at(const void* ei, int is64, long long pos) {
    if (is64) return (int)((const long long*)ei)[pos];
    return ((const int*)ei)[pos];
}

// Inline int64/int32 detection (hi word of int64 indices < 2^17 is always 0).
__device__ __forceinline__ int detect_is64(const unsigned* ei, int* s_is64) {
    if (threadIdx.x < 64) {
        unsigned v = ei[2 * threadIdx.x + 1];
        unsigned long long nz = __ballot(v != 0u);
        if (threadIdx.x == 0) *s_is64 = (nz == 0ull) ? 1 : 0;
    }
    __syncthreads();
    return *s_is64;
}

// ---------------------------------------------------------------------------
// Pass A: stage chunk in LDS packed (src | dst<<16), LDS hist over dst>>8,
// LDS scan, LDS bucket-sort, coalesced write-out.
// Emits: pairs_cs[w*CHUNK + i], H[b*NB+w] (run length), L[b*NB+w] (run start).
// ---------------------------------------------------------------------------
__global__ __launch_bounds__(256) void passA_kernel(const void* ei,
                                                    unsigned* __restrict__ H,
                                                    unsigned* __restrict__ L,
                                                    unsigned* __restrict__ pairs_cs) {
    __shared__ unsigned ed[CHUNK];
    __shared__ unsigned srt[CHUNK];
    __shared__ unsigned hist[NB];
    __shared__ unsigned scn[NB];
    __shared__ int s_is64;
    const int is64 = detect_is64((const unsigned*)ei, &s_is64);
    const int t = threadIdx.x;
    const int w = blockIdx.x;
    hist[t] = 0;
    __syncthreads();
    const int base = w * CHUNK;
    for (int i = t; i < CHUNK; i += 256) {
        unsigned src = (unsigned)edge_at(ei, is64, base + i);
        unsigned dst = (unsigned)edge_at(ei, is64, (long long)N_EDGES + base + i);
        ed[i] = src | (dst << 16);
        atomicAdd(&hist[dst >> 8], 1u);
    }
    __syncthreads();
    const unsigned own = hist[t];
    scn[t] = own;
    __syncthreads();
    for (int off = 1; off < NB; off <<= 1) {
        unsigned v = (t >= off) ? scn[t - off] : 0u;
        __syncthreads();
        scn[t] += v;
        __syncthreads();
    }
    const unsigned excl = scn[t] - own;
    H[t * NB + w] = own;
    L[t * NB + w] = excl;
    hist[t] = excl;  // reuse as cursor
    __syncthreads();
    for (int i = t; i < CHUNK; i += 256) {
        unsigned p = ed[i];
        unsigned pos = atomicAdd(&hist[p >> 24], 1u);  // bucket = dst>>8 = p>>24
        srt[pos] = p;
    }
    __syncthreads();
    for (int i = t; i < CHUNK; i += 256) pairs_cs[(size_t)w * CHUNK + i] = srt[i];
}

// ---------------------------------------------------------------------------
// Pass B: bucket totals via per-thread H row-sum, LDS scan -> bucket_start;
// gather this bucket's 256 chunk-runs into LDS, hist over dstlow (== deg),
// LDS scan -> row_start, LDS sort -> coalesced u16 src16, prefolded bf16 y.
// ---------------------------------------------------------------------------
__global__ __launch_bounds__(256) void bucketB_kernel(const unsigned* __restrict__ pairs_cs,
                                                      const unsigned* __restrict__ H,
                                                      const unsigned* __restrict__ L,
                                                      const float* __restrict__ x,
                                                      unsigned* __restrict__ row_start,
                                                      unsigned short* __restrict__ src16,
                                                      unsigned* __restrict__ y32,
                                                      unsigned* __restrict__ fb) {
    __shared__ unsigned s_pairs[SSTAGE];
    __shared__ unsigned short s_src[SSTAGE];
    __shared__ unsigned hist[NB];
    __shared__ unsigned scn[NB];
    __shared__ unsigned degs[NB];
    __shared__ unsigned s_tot[NB];
    const int t = threadIdx.x;
    const int b = blockIdx.x;

    // bucket totals: thread t sums H[t][*] (1 KB contiguous, L2-hit).
    {
        const uint4* Hr = (const uint4*)(H + t * NB);
        unsigned tt = 0;
#pragma unroll 8
        for (int k = 0; k < NB / 4; ++k) {
            uint4 q = Hr[k];
            tt += q.x + q.y + q.z + q.w;
        }
        s_tot[t] = tt;
        scn[t] = tt;
    }
    __syncthreads();
    for (int off = 1; off < NB; off <<= 1) {
        unsigned v = (t >= off) ? scn[t - off] : 0u;
        __syncthreads();
        scn[t] += v;
        __syncthreads();
    }
    const unsigned base = scn[b] - s_tot[b];
    const unsigned cnt = s_tot[b];
    const bool staged = (cnt <= SSTAGE);
    __syncthreads();

    // run-gather: thread t copies chunk t's run for this bucket.
    const unsigned Hb = H[b * NB + t];
    const unsigned Lb = L[b * NB + t];
    scn[t] = Hb;
    __syncthreads();
    for (int off = 1; off < NB; off <<= 1) {
        unsigned v = (t >= off) ? scn[t - off] : 0u;
        __syncthreads();
        scn[t] += v;
        __syncthreads();
    }
    const unsigned ex = scn[t] - Hb;
    unsigned* wp = staged ? s_pairs : (fb + (size_t)b * FBCAP);
    for (unsigned j = 0; j < Hb; ++j) wp[ex + j] = pairs_cs[(size_t)t * CHUNK + Lb + j];
    __syncthreads();
    const unsigned* pp = staged ? s_pairs : (fb + (size_t)b * FBCAP);

    hist[t] = 0;
    __syncthreads();
    for (unsigned i = t; i < cnt; i += 256u) {
        atomicAdd(&hist[(pp[i] >> 16) & 255u], 1u);
    }
    __syncthreads();
    const unsigned own = hist[t];
    degs[t] = own;
    scn[t] = own;
    __syncthreads();
    for (int off = 1; off < NB; off <<= 1) {
        unsigned v = (t >= off) ? scn[t - off] : 0u;
        __syncthreads();
        scn[t] += v;
        __syncthreads();
    }
    const unsigned excl = scn[t] - own;
    row_start[b * NB + t] = base + excl;
    if (b == NB - 1 && t == 0) row_start[N_NODES] = N_EDGES;
    hist[t] = excl;  // reuse as cursor
    __syncthreads();
    if (staged) {
        for (unsigned i = t; i < cnt; i += 256u) {
            unsigned p = pp[i];
            unsigned pos = atomicAdd(&hist[(p >> 16) & 255u], 1u);
            s_src[pos] = (unsigned short)(p & 0xFFFFu);
        }
        __syncthreads();
        for (unsigned i = t; i < cnt; i += 256u) src16[base + i] = s_src[i];
    } else {  // statistically unreachable
        for (unsigned i = t; i < cnt; i += 256u) {
            unsigned p = pp[i];
            unsigned pos = atomicAdd(&hist[(p >> 16) & 255u], 1u);
            src16[base + pos] = (unsigned short)(p & 0xFFFFu);
        }
    }
    // y phase: y[n][d] = bf16(rsqrt(deg[n]) * x[n][d]), unified layout.
    const int nbase = b * NB;
    for (int idx = t; idx < NB * 32; idx += 256) {
        int nl = idx >> 5;
        int col = idx & 31;               // u32 column (2 feats each)
        unsigned d = degs[nl];
        float w = d ? rsqrtf((float)d) : 0.f;
        float2 v = *(const float2*)(x + (nbase + nl) * D + col * 2);
        unsigned lo = (unsigned)__builtin_bit_cast(unsigned short, (__bf16)(v.x * w));
        unsigned hi = (unsigned)__builtin_bit_cast(unsigned short, (__bf16)(v.y * w));
        y32[(size_t)(nbase + nl) * 32 + col] = lo | (hi << 16);
    }
}

// ---------------------------------------------------------------------------
// Atomic-free segmented SpMM, NO cross-lane reduction (round-13 proven).
// Wave = 8 nodes x 8 lanes: group g owns node nb+g, lane r8 owns feature
// chunk [8*r8, 8*r8+8); serial edge walk, unroll-4. Store = one coalesced
// 1 KB line per wave.
// ---------------------------------------------------------------------------
#define BLO(u) __uint_as_float((u) << 16)
#define BHI(u) __uint_as_float((u) & 0xffff0000u)
__device__ __forceinline__ unsigned pkbf(float lo, float hi) {
    return (unsigned)__builtin_bit_cast(unsigned short, (__bf16)lo) |
           ((unsigned)__builtin_bit_cast(unsigned short, (__bf16)hi) << 16);
}
__device__ __forceinline__ void acc8(uint4 p, float* a) {
    a[0] += BLO(p.x); a[1] += BHI(p.x);
    a[2] += BLO(p.y); a[3] += BHI(p.y);
    a[4] += BLO(p.z); a[5] += BHI(p.z);
    a[6] += BLO(p.w); a[7] += BHI(p.w);
}
__global__ __launch_bounds__(256) void spmm_kernel(const unsigned short* __restrict__ src16,
                                                   const unsigned* __restrict__ row_start,
                                                   const uint4* __restrict__ y128,
                                                   uint4* __restrict__ hb4) {
    const int lane = threadIdx.x & 63;
    const int g = lane >> 3;     // node slot 0..7
    const int r8 = lane & 7;     // feature chunk [8*r8, 8*r8+8)
    int wv = (blockIdx.x * blockDim.x + threadIdx.x) >> 6;
    int nwv = (gridDim.x * blockDim.x) >> 6;
    for (int nb = wv * 8; nb < N_NODES; nb += nwv * 8) {
        const int n = nb + g;
        const unsigned start = row_start[n];
        const unsigned end = row_start[n + 1];
        float a[8] = {0.f, 0.f, 0.f, 0.f, 0.f, 0.f, 0.f, 0.f};
        float c[8] = {0.f, 0.f, 0.f, 0.f, 0.f, 0.f, 0.f, 0.f};
        unsigned i = start;
        for (; i + 4 <= end; i += 4) {
            int s0 = (int)src16[i];
            int s1 = (int)src16[i + 1];
            int s2 = (int)src16[i + 2];
            int s3 = (int)src16[i + 3];
            uint4 p0 = y128[s0 * 8 + r8];
            uint4 p1 = y128[s1 * 8 + r8];
            uint4 p2 = y128[s2 * 8 + r8];
            uint4 p3 = y128[s3 * 8 + r8];
            acc8(p0, a); acc8(p1, c);
            acc8(p2, a); acc8(p3, c);
        }
        for (; i < end; ++i) {
            uint4 p = y128[(int)src16[i] * 8 + r8];
            acc8(p, a);
        }
        const float w = (end > start) ? rsqrtf((float)(end - start)) : 0.f;
        uint4 v;
        v.x = pkbf((a[0] + c[0]) * w, (a[1] + c[1]) * w);
        v.y = pkbf((a[2] + c[2]) * w, (a[3] + c[3]) * w);
        v.z = pkbf((a[4] + c[4]) * w, (a[5] + c[5]) * w);
        v.w = pkbf((a[6] + c[6]) * w, (a[7] + c[7]) * w);
        hb4[(size_t)nb * 8 + lane] = v;  // n*8 + r8 == nb*8 + lane
    }
}

// ---------------------------------------------------------------------------
// out = leaky(h@W1+b1) + leaky((x*h)@W2+b2) via mfma_f32_16x16x32_bf16.
// x is NOT read: x~ = y * sqrt(deg) (y is bf16 of rsqrt(deg)*x; cache-warm
// from spmm). Zero-deg rows: y=0 & h=0 -> g=0, exact. deg from row_start.
// ---------------------------------------------------------------------------
__global__ __launch_bounds__(256) void dense_mfma_kernel(const uint4* __restrict__ y128,
                                                         const uint4* __restrict__ hb4,
                                                         const unsigned* __restrict__ row_start,
                                                         const float* __restrict__ W1,
                                                         const float* __restrict__ b1,
                                                         const float* __restrict__ W2,
                                                         const float* __restrict__ b2,
                                                         float* __restrict__ out) {
    const int lane = threadIdx.x & 63;
    const int lo = lane & 15;
    const int hi = lane >> 4;

    bf16x8 bw1[2][4], bw2[2][4];
#pragma unroll
    for (int kt = 0; kt < 2; ++kt)
#pragma unroll
        for (int nt = 0; nt < 4; ++nt) {
            bf16x8 v1, v2;
#pragma unroll
            for (int j = 0; j < 8; ++j) {
                int k = kt * 32 + hi * 8 + j;
                int n = nt * 16 + lo;
                v1[j] = (__bf16)W1[k * D + n];
                v2[j] = (__bf16)W2[k * D + n];
            }
            bw1[kt][nt] = v1;
            bw2[kt][nt] = v2;
        }
    float bb1[4], bb2[4];
#pragma unroll
    for (int nt = 0; nt < 4; ++nt) {
        bb1[nt] = b1[nt * 16 + lo];
        bb2[nt] = b2[nt * 16 + lo];
    }

    int wid = (blockIdx.x * blockDim.x + threadIdx.x) >> 6;
    int nw = (gridDim.x * blockDim.x) >> 6;
    for (int blk = wid; blk < N_NODES / 16; blk += nw) {
        const int rb = blk * 16;
        const int row = rb + lo;
        const uint4* hrow = hb4 + (size_t)row * 8;
        const uint4* yrow = y128 + (size_t)row * 8;
        const float sd = sqrtf((float)(row_start[row + 1] - row_start[row]));
        bf16x8 ah[2], ag[2];
#pragma unroll
        for (int kt = 0; kt < 2; ++kt) {
            uint4 hp = hrow[kt * 4 + hi];
            uint4 yp = yrow[kt * 4 + hi];
            ah[kt] = __builtin_bit_cast(bf16x8, hp);
            bf16x8 g;
            g[0] = (__bf16)(BLO(hp.x) * (BLO(yp.x) * sd));
            g[1] = (__bf16)(BHI(hp.x) * (BHI(yp.x) * sd));
            g[2] = (__bf16)(BLO(hp.y) * (BLO(yp.y) * sd));
            g[3] = (__bf16)(BHI(hp.y) * (BHI(yp.y) * sd));
            g[4] = (__bf16)(BLO(hp.z) * (BLO(yp.z) * sd));
            g[5] = (__bf16)(BHI(hp.z) * (BHI(yp.z) * sd));
            g[6] = (__bf16)(BLO(hp.w) * (BLO(yp.w) * sd));
            g[7] = (__bf16)(BHI(hp.w) * (BHI(yp.w) * sd));
            ag[kt] = g;
        }
        f32x4 acc1[4], acc2[4];
#pragma unroll
        for (int nt = 0; nt < 4; ++nt) {
            acc1[nt] = (f32x4){0.f, 0.f, 0.f, 0.f};
            acc2[nt] = (f32x4){0.f, 0.f, 0.f, 0.f};
        }
#pragma unroll
        for (int kt = 0; kt < 2; ++kt)
#pragma unroll
            for (int nt = 0; nt < 4; ++nt) {
                acc1[nt] = __builtin_amdgcn_mfma_f32_16x16x32_bf16(ah[kt], bw1[kt][nt], acc1[nt], 0, 0, 0);
                acc2[nt] = __builtin_amdgcn_mfma_f32_16x16x32_bf16(ag[kt], bw2[kt][nt], acc2[nt], 0, 0, 0);
            }
#pragma unroll
        for (int nt = 0; nt < 4; ++nt)
#pragma unroll
            for (int r = 0; r < 4; ++r) {
                float a1 = acc1[nt][r] + bb1[nt];
                float a2 = acc2[nt][r] + bb2[nt];
                a1 = (a1 >= 0.f) ? a1 : 0.2f * a1;
                a2 = (a2 >= 0.f) ? a2 : 0.2f * a2;
                out[(rb + hi * 4 + r) * D + nt * 16 + lo] = a1 + a2;
            }
    }
}

extern "C" void kernel_launch(void* const* d_in, const int* in_sizes, int n_in,
                              void* d_out, int out_size, void* d_ws, size_t ws_size,
                              hipStream_t stream) {
    const float* x  = (const float*)d_in[0];
    const void*  ei = d_in[1];
    const float* W1 = (const float*)d_in[2];
    const float* b1 = (const float*)d_in[3];
    const float* W2 = (const float*)d_in[4];
    const float* b2 = (const float*)d_in[5];
    float* out = (float*)d_out;

    char* p = (char*)d_ws;
    unsigned* row_start    = (unsigned*)p;       p += 266240;          // 65537 u32
    unsigned* H            = (unsigned*)p;       p += NB * NB * 4;     // 256 KB
    unsigned* L            = (unsigned*)p;       p += NB * NB * 4;     // 256 KB
    unsigned short* src16  = (unsigned short*)p; p += (size_t)N_EDGES * 2;      // 2 MB
    unsigned* y32          = (unsigned*)p;       p += (size_t)N_NODES * 32 * 4; // 8 MB
    unsigned* hb           = (unsigned*)p;       p += (size_t)N_NODES * 32 * 4; // 8 MB
    unsigned* fb           = (unsigned*)p;       // 64 MB fallback (rarely touched)

    // pairs_cs scratch lives in d_out: written by passA, consumed by bucketB,
    // then d_out is fully overwritten by dense_mfma. Deterministic modulo
    // intra-run LDS-atomic order (rounding-level only, as in prior rounds).
    unsigned* pairs_cs = (unsigned*)d_out;

    passA_kernel<<<NB, 256, 0, stream>>>(ei, H, L, pairs_cs);
    bucketB_kernel<<<NB, 256, 0, stream>>>(pairs_cs, H, L, x, row_start, src16, y32, fb);
    spmm_kernel<<<2048, 256, 0, stream>>>(src16, row_start, (const uint4*)y32, (uint4*)hb);
    dense_mfma_kernel<<<1024, 256, 0, stream>>>((const uint4*)y32, (const uint4*)hb,
                                                row_start, W1, b1, W2, b2, out);
}